// Round 11
// baseline (205.011 us; speedup 1.0000x reference)
//
#include <hip/hip_runtime.h>

#define SB   2048   // sequence length S
#define DD   1024   // model dim D
#define NH   16     // heads
#define HDIM 64     // head dim
#define NB   2      // batch

typedef float f4 __attribute__((ext_vector_type(4)));
typedef __bf16 bf16x8 __attribute__((ext_vector_type(8)));
typedef unsigned short u16;
typedef unsigned int u32;
typedef unsigned long long u64;
typedef u16 u16x8 __attribute__((ext_vector_type(8)));
typedef u16 u16x4 __attribute__((ext_vector_type(4)));

// Q is pre-scaled by 1/sqrt(HD) * log2(e) so attention works in exp2 domain.
#define QSCALE 0.1803368801111f

__device__ __forceinline__ u16 f2bf(float f) {
  unsigned u = __float_as_uint(f);
  u += 0x7FFFu + ((u >> 16) & 1u);   // RNE to bf16
  return (u16)(u >> 16);
}

// async global->LDS, 16 B per lane; LDS dest = base + lane*16 (wave-uniform base)
typedef __attribute__((address_space(3))) unsigned int lds_uint;
typedef __attribute__((address_space(1))) const unsigned int glb_uint;
__device__ __forceinline__ void gl_lds16(const void* g, void* l) {
  __builtin_amdgcn_global_load_lds((glb_uint*)g, (lds_uint*)l, 16, 0, 0);
}

__device__ __forceinline__ void cvt8(const float* __restrict__ src,
                                     u16* __restrict__ dst, size_t i) {
  f4 a = *(const f4*)(src + 8 * i);
  f4 b = *(const f4*)(src + 8 * i + 4);
  u16x8 o;
  o[0] = f2bf(a[0]); o[1] = f2bf(a[1]); o[2] = f2bf(a[2]); o[3] = f2bf(a[3]);
  o[4] = f2bf(b[0]); o[5] = f2bf(b[1]); o[6] = f2bf(b[2]); o[7] = f2bf(b[3]);
  *(u16x8*)(dst + 8 * i) = o;
}

// ------- prep: x cvt + Wq/Wk/Wv cvt + Wo cvt + RoPE tables, one dispatch --
__global__ __launch_bounds__(256) void prep_kernel(
    const float* __restrict__ x, const float* __restrict__ Wq,
    const float* __restrict__ Wk, const float* __restrict__ Wv,
    const float* __restrict__ Wo,
    u16* __restrict__ xb, u16* __restrict__ Wb3, u16* __restrict__ Wob,
    float* __restrict__ cosT, float* __restrict__ sinT) {
  int bid = blockIdx.x, t = threadIdx.x;
  if (bid < 2048) {
    cvt8(x, xb, (size_t)bid * 256 + t);
  } else if (bid < 2560) {
    cvt8(Wq, Wb3, (size_t)(bid - 2048) * 256 + t);
  } else if (bid < 3072) {
    cvt8(Wk, Wb3 + (1u << 20), (size_t)(bid - 2560) * 256 + t);
  } else if (bid < 3584) {
    cvt8(Wv, Wb3 + (2u << 20), (size_t)(bid - 3072) * 256 + t);
  } else if (bid < 4096) {
    cvt8(Wo, Wob, (size_t)(bid - 3584) * 256 + t);
  } else {
    int idx = (bid - 4096) * 256 + t;        // 0..65535 = S*32
    int tt = idx & 31, s = idx >> 5;
    float inv = powf(10000.0f, -2.0f * (float)tt / 64.0f);
    float ang = (float)s * inv;
    cosT[idx] = cosf(ang);
    sinT[idx] = sinf(ang);
  }
}

// ---------------- Fused QKV GEMM: 128x128 tile, BK=64 ---------------------
// A: xb (4096,1024) bf16. W3: stacked [Wq;Wk;Wv] (3072,1024) bf16.
// grid (32,24). Wave: 64x64 quadrant, 4x4 frags x 2 k-halves = 32 MFMA/iter.
// LDS: granule swizzle phys = lg ^ (row & 7) (8 granules/row) -> 2-way free.
__global__ __launch_bounds__(256) void gemm_qkv_fused_kernel(
    const u16* __restrict__ A, const u16* __restrict__ W3,
    const float* __restrict__ bq, const float* __restrict__ bk,
    const float* __restrict__ bv,
    u16* __restrict__ Qw, u16* __restrict__ Kw, u16* __restrict__ Vt,
    const float* __restrict__ cosT, const float* __restrict__ sinT) {
  const int K = DD;
  __shared__ u16 As[128 * 64];   // 16 KB
  __shared__ u16 Bs[128 * 64];   // 16 KB
  const int t = threadIdx.x;
  const int wave = t >> 6, lane = t & 63;
  const int m0 = blockIdx.x * 128, n0 = blockIdx.y * 128;
  const int mw = (wave >> 1) * 64, nw = (wave & 1) * 64;
  const int quad = lane >> 4, l15 = lane & 15;
  const int srow = lane >> 3, sgran = lane & 7;   // staging: 8 rows x 8 granules
  const u16* Ab = A + (size_t)m0 * K;
  const u16* Bb = W3 + (size_t)n0 * K;
  f4 acc[4][4];
#pragma unroll
  for (int i = 0; i < 4; i++)
#pragma unroll
    for (int j = 0; j < 4; j++) acc[i][j] = (f4)0.f;

  for (int kt = 0; kt < K; kt += 64) {
#pragma unroll
    for (int is = 0; is < 4; is++) {
      int r = wave * 32 + is * 8 + srow;
      int lg = sgran ^ (r & 7);
      gl_lds16(Ab + (size_t)r * K + kt + lg * 8, &As[(wave * 32 + is * 8) * 64]);
      gl_lds16(Bb + (size_t)r * K + kt + lg * 8, &Bs[(wave * 32 + is * 8) * 64]);
    }
    __syncthreads();
#pragma unroll
    for (int kh = 0; kh < 2; kh++) {
      bf16x8 af[4], bfr[4];
#pragma unroll
      for (int i = 0; i < 4; i++) {
        int R = mw + 16 * i + l15;
        af[i] = *(const bf16x8*)&As[R * 64 + ((kh * 4 + quad) ^ (R & 7)) * 8];
        int Rb = nw + 16 * i + l15;
        bfr[i] = *(const bf16x8*)&Bs[Rb * 64 + ((kh * 4 + quad) ^ (Rb & 7)) * 8];
      }
#pragma unroll
      for (int i = 0; i < 4; i++)
#pragma unroll
        for (int j = 0; j < 4; j++)
          acc[i][j] = __builtin_amdgcn_mfma_f32_16x16x32_bf16(af[i], bfr[j],
                                                              acc[i][j], 0, 0, 0);
    }
    __syncthreads();
  }

  // epilogue: route per column group (which is wave-uniform per j)
#pragma unroll
  for (int j = 0; j < 4; j++) {
    int colg3 = n0 + nw + 16 * j + l15;
    int which = colg3 >> 10;                      // 0=Q 1=K 2=V
    int c = colg3 & 1023;
    int h = c >> 6, dh = c & 63, tt2 = dh >> 1;
    float bval = (which == 0 ? bq : which == 1 ? bk : bv)[c];
    if (which == 2) {
#pragma unroll
      for (int i = 0; i < 4; i++) {
        int mg0 = m0 + mw + 16 * i + quad * 4;
        int b = mg0 >> 11, sr0 = mg0 & (SB - 1);
        u16x4 pk4;
#pragma unroll
        for (int r = 0; r < 4; r++) pk4[r] = f2bf(acc[i][j][r] + bval);
        *(u16x4*)(Vt + ((size_t)(b * NH + h) * HDIM + dh) * SB + sr0) = pk4;
      }
    } else {
      u16* dst = which ? Kw : Qw;
      float scale = which ? 1.0f : QSCALE;
#pragma unroll
      for (int i = 0; i < 4; i++)
#pragma unroll
        for (int r = 0; r < 4; r++) {
          int mg = m0 + mw + 16 * i + quad * 4 + r;
          int b = mg >> 11, sr = mg & (SB - 1);
          float v = acc[i][j][r] + bval;
          float vp = __shfl_xor(v, 1);            // RoPE pair partner column
          float cc = cosT[sr * 32 + tt2], ss = sinT[sr * 32 + tt2];
          v = ((lane & 1) == 0) ? (v * cc - vp * ss) : (vp * ss + v * cc);
          dst[(((size_t)(b * NH + h)) * SB + sr) * HDIM + dh] = f2bf(v * scale);
        }
    }
  }
}

// ---------------- Output projection GEMM: 128x64 tile, BK=64 --------------
__global__ __launch_bounds__(256) void gemm_out_kernel(
    const u16* __restrict__ A, const u16* __restrict__ W,
    const float* __restrict__ bias, float* __restrict__ outp) {
  const int K = DD;
  __shared__ u16 As[128 * 64];   // 16 KB
  __shared__ u16 Bs[64 * 64];    // 8 KB
  const int t = threadIdx.x;
  const int wave = t >> 6, lane = t & 63;
  const int m0 = blockIdx.x * 128, n0 = blockIdx.y * 64;
  const int mw = (wave >> 1) * 64, nw = (wave & 1) * 32;
  const int quad = lane >> 4, l15 = lane & 15;
  const int srow = lane >> 3, sgran = lane & 7;
  const u16* Ab = A + (size_t)m0 * K;
  const u16* Bb = W + (size_t)n0 * K;
  f4 acc[4][2];
#pragma unroll
  for (int i = 0; i < 4; i++)
#pragma unroll
    for (int j = 0; j < 2; j++) acc[i][j] = (f4)0.f;

  for (int kt = 0; kt < K; kt += 64) {
#pragma unroll
    for (int is = 0; is < 4; is++) {
      int r = wave * 32 + is * 8 + srow;
      int lg = sgran ^ (r & 7);
      gl_lds16(Ab + (size_t)r * K + kt + lg * 8, &As[(wave * 32 + is * 8) * 64]);
    }
#pragma unroll
    for (int is = 0; is < 2; is++) {
      int r = wave * 16 + is * 8 + srow;
      int lg = sgran ^ (r & 7);
      gl_lds16(Bb + (size_t)r * K + kt + lg * 8, &Bs[(wave * 16 + is * 8) * 64]);
    }
    __syncthreads();
#pragma unroll
    for (int kh = 0; kh < 2; kh++) {
      bf16x8 af[4], bfr[2];
#pragma unroll
      for (int i = 0; i < 4; i++) {
        int R = mw + 16 * i + l15;
        af[i] = *(const bf16x8*)&As[R * 64 + ((kh * 4 + quad) ^ (R & 7)) * 8];
      }
#pragma unroll
      for (int j = 0; j < 2; j++) {
        int R = nw + 16 * j + l15;
        bfr[j] = *(const bf16x8*)&Bs[R * 64 + ((kh * 4 + quad) ^ (R & 7)) * 8];
      }
#pragma unroll
      for (int i = 0; i < 4; i++)
#pragma unroll
        for (int j = 0; j < 2; j++)
          acc[i][j] = __builtin_amdgcn_mfma_f32_16x16x32_bf16(af[i], bfr[j],
                                                              acc[i][j], 0, 0, 0);
    }
    __syncthreads();
  }
#pragma unroll
  for (int i = 0; i < 4; i++)
#pragma unroll
    for (int j = 0; j < 2; j++) {
      int colg = n0 + nw + 16 * j + l15;
#pragma unroll
      for (int r = 0; r < 4; r++) {
        int mg = m0 + mw + 16 * i + quad * 4 + r;
        outp[(size_t)mg * DD + colg] = acc[i][j][r] + bias[colg];
      }
    }
}

// ----- MFMA flash attention: paired Q-tiles + in-block K-split x2 ---------
// grid (8, H, B), 1024 threads = 16 waves. kh2 = w>>3 picks K-split half
// (even / odd 64-col tiles); within a half, waves 0-3 -> Q-tile qp (light),
// waves 4-7 -> mirror tile 15-qp (heavy); wl = strip-pair. Each half has its
// own double-buffered LDS K/V staging (fragment order). Fixed-reference
// softmax (M=0) makes the cross-half merge a PURE SUM (exact): O=O0+O1,
// l=l0+l1, exchanged through LDS in two strip-phases at the end.
__global__ __launch_bounds__(1024) void attn_mfma_kernel(
    const u16* __restrict__ Qw, const u16* __restrict__ Kw,
    const u16* __restrict__ Vt, u16* __restrict__ Ow,
    const int* __restrict__ eff) {
  __shared__ u16 SMEM[2][2][2][4096];   // [K/V][half][buf][frag*512+lane*8] 64 KB
  const int w = threadIdx.x >> 6, lane = threadIdx.x & 63;
  const int l15 = lane & 15, q4 = lane >> 4;
  const int kh2 = w >> 3;                                // K-split half
  const int wr = w & 7;                                  // role within half
  const int wg = wr >> 2, wl = wr & 3;
  const int qp = blockIdx.x;                             // 0..7
  const int QT = wg ? (SB / 128 - 1 - qp) : qp;          // light / heavy pair
  const int h = blockIdx.y, b = blockIdx.z;
  const int limit = SB - eff[b];                         // valid cols [0, limit)
  const size_t bh = ((size_t)b * NH + h) * (SB * HDIM);

  const int rowbase = QT * 128 + wl * 32;

  // Q^T fragments for both strips, kept in registers for the whole kernel
  bf16x8 qf[2][2];
  {
    const u16* qp0 = Qw + bh + (size_t)(rowbase + l15) * HDIM + q4 * 8;
    qf[0][0] = *(const bf16x8*)qp0;
    qf[0][1] = *(const bf16x8*)(qp0 + 32);
    const u16* qp1 = qp0 + 16 * HDIM;
    qf[1][0] = *(const bf16x8*)qp1;
    qf[1][1] = *(const bf16x8*)(qp1 + 32);
  }

  f4 acc[2][4];
#pragma unroll
  for (int s = 0; s < 2; s++)
#pragma unroll
    for (int dt = 0; dt < 4; dt++) acc[s][dt] = (f4)0.f;
  float l_run[2] = {0.f, 0.f};   // per-lane partial row sums

  // block-uniform tile count = heavy tile's k-range
  const int kendB = min((SB / 128 - 1 - qp) * 128 + 127, limit - 1);
  const int ntiles = (kendB >> 6) + 1;                   // >= 17 (limit >= 1025)
  const int ntmax = (ntiles + 1) >> 1;                   // uniform barrier count
  // this wave's last needed column (wave-uniform compute skip)
  const int wkend = min(rowbase + 31, limit - 1);

  // stage(tile, buf) for this half: waves wr 0-3 stage K frags 0..7,
  // waves wr 4-7 stage V frags 0..7 (2 gl_lds16 per wave).
  // K frag fk=(mt*2+j): global = K[colb + mt*16 + l15][q4*8 + j*32]
  // V frag fv=(dt*2+j): global = Vt[dt*16 + l15][colb + q4*8 + j*32]
#define STAGE_TILE(TILE, BUF)                                                   \
  {                                                                             \
    const int colb_ = (TILE) * 64;                                              \
    _Pragma("unroll") for (int f = 0; f < 2; f++) {                             \
      int fr = wr * 2 + f;                                                      \
      if (fr < 8) {                                                             \
        int mt = fr >> 1, j = fr & 1;                                           \
        gl_lds16(Kw + bh + (size_t)(colb_ + mt * 16 + l15) * HDIM + q4 * 8 + j * 32, \
                 &SMEM[0][kh2][BUF][fr * 512]);                                 \
      } else {                                                                  \
        int fv = fr - 8, dt = fv >> 1, j = fv & 1;                              \
        gl_lds16(Vt + bh + (size_t)(dt * 16 + l15) * SB + colb_ + q4 * 8 + j * 32, \
                 &SMEM[1][kh2][BUF][fv * 512]);                                 \
      }                                                                         \
    }                                                                           \
  }

  STAGE_TILE(kh2, 0)   // first tile of this half (exists: ntiles >= 2)
  __syncthreads();

  for (int i = 0; i < ntmax; i++) {
    const int kt = 2 * i + kh2;
    const int cur = i & 1;
    const int colb = kt * 64;
    const bool have = (kt < ntiles);
    if (kt + 2 < ntiles) STAGE_TILE(kt + 2, cur ^ 1)

    if (have && colb <= wkend) {   // wave-uniform
      // ---- S^T = K · Q^T for both strips (K frags from LDS) ----
      f4 sa[2][4];
#pragma unroll
      for (int mt = 0; mt < 4; mt++) {
        bf16x8 k0 = *(const bf16x8*)&SMEM[0][kh2][cur][(mt * 2 + 0) * 512 + lane * 8];
        bf16x8 k1 = *(const bf16x8*)&SMEM[0][kh2][cur][(mt * 2 + 1) * 512 + lane * 8];
        f4 s0 = (f4)0.f, s1 = (f4)0.f;
        s0 = __builtin_amdgcn_mfma_f32_16x16x32_bf16(k0, qf[0][0], s0, 0, 0, 0);
        s0 = __builtin_amdgcn_mfma_f32_16x16x32_bf16(k1, qf[0][1], s0, 0, 0, 0);
        s1 = __builtin_amdgcn_mfma_f32_16x16x32_bf16(k0, qf[1][0], s1, 0, 0, 0);
        s1 = __builtin_amdgcn_mfma_f32_16x16x32_bf16(k1, qf[1][1], s1, 0, 0, 0);
        sa[0][mt] = s0;
        sa[1][mt] = s1;
      }

      // ---- mask + fixed-reference softmax weights per strip ----
      u32 pk[2][4][2];
#pragma unroll
      for (int s = 0; s < 2; s++) {
        const int rb = rowbase + 16 * s;
        const int rg = rb + l15;
        const bool needmask = (colb + 63 > rb) || (colb + 63 >= limit);
        if (needmask) {
#pragma unroll
          for (int mt = 0; mt < 4; mt++)
#pragma unroll
            for (int r = 0; r < 4; r++) {
              int col = colb + mt * 16 + q4 * 4 + r;
              if (col > rg || col >= limit) sa[s][mt][r] = -3.0e38f;
            }
        }
        float lsum = 0.f;
#pragma unroll
        for (int mt = 0; mt < 4; mt++) {
          float p0 = exp2f(sa[s][mt][0]);   // masked -> exp2(-3e38) = 0 exactly
          float p1 = exp2f(sa[s][mt][1]);
          float p2 = exp2f(sa[s][mt][2]);
          float p3 = exp2f(sa[s][mt][3]);
          lsum += (p0 + p1) + (p2 + p3);
          pk[s][mt][0] = (__float_as_uint(p1) & 0xFFFF0000u) | (__float_as_uint(p0) >> 16);
          pk[s][mt][1] = (__float_as_uint(p3) & 0xFFFF0000u) | (__float_as_uint(p2) >> 16);
        }
        l_run[s] += lsum;
      }

      // ---- P^T relayout (C-layout -> B-operand) + PV (V frags from LDS) ----
      const int srcA = ((q4 & 1) << 5) + l15;
      const int hi = q4 >> 1;
#pragma unroll
      for (int s = 0; s < 2; s++) {
        union { u32 wds[4]; bf16x8 v; } ub0, ub1;
#pragma unroll
        for (int d = 0; d < 4; d++) {
          int src = srcA + ((d >> 1) << 4);
          u32 t0 = (u32)__shfl((int)pk[s][0][d & 1], src);
          u32 t1 = (u32)__shfl((int)pk[s][1][d & 1], src);
          ub0.wds[d] = hi ? t1 : t0;
          u32 t2 = (u32)__shfl((int)pk[s][2][d & 1], src);
          u32 t3 = (u32)__shfl((int)pk[s][3][d & 1], src);
          ub1.wds[d] = hi ? t3 : t2;
        }
#pragma unroll
        for (int dt = 0; dt < 4; dt++) {
          bf16x8 v0 = *(const bf16x8*)&SMEM[1][kh2][cur][(dt * 2 + 0) * 512 + lane * 8];
          bf16x8 v1 = *(const bf16x8*)&SMEM[1][kh2][cur][(dt * 2 + 1) * 512 + lane * 8];
          acc[s][dt] = __builtin_amdgcn_mfma_f32_16x16x32_bf16(v0, ub0.v, acc[s][dt], 0, 0, 0);
          acc[s][dt] = __builtin_amdgcn_mfma_f32_16x16x32_bf16(v1, ub1.v, acc[s][dt], 0, 0, 0);
        }
      }
    }
    __syncthreads();   // reads of buf cur done; prefetch into cur^1 drained
  }

  // ---- cross-half merge (pure sum; fixed-ref softmax) in 2 strip-phases ----
  float* XCH = (float*)&SMEM[0][0][0][0];   // 64 KB scratch; need 34.8 KB/phase
  const int xidx = (wr * 64 + lane) * 17;
#pragma unroll
  for (int s = 0; s < 2; s++) {
    if (kh2 == 1) {
#pragma unroll
      for (int dt = 0; dt < 4; dt++)
#pragma unroll
        for (int r = 0; r < 4; r++) XCH[xidx + dt * 4 + r] = acc[s][dt][r];
      XCH[xidx + 16] = l_run[s];
    }
    __syncthreads();
    if (kh2 == 0) {
#pragma unroll
      for (int dt = 0; dt < 4; dt++)
#pragma unroll
        for (int r = 0; r < 4; r++) acc[s][dt][r] += XCH[xidx + dt * 4 + r];
      l_run[s] += XCH[xidx + 16];
    }
    __syncthreads();
  }

  // ---- epilogue (half 0 only): reduce l, normalize, store (B,S,H,HD) ----
  if (kh2 == 0) {
#pragma unroll
    for (int s = 0; s < 2; s++) {
      float lt = l_run[s];
      lt += __shfl_xor(lt, 16);
      lt += __shfl_xor(lt, 32);
      const float linv = 1.0f / lt;
      const int rg = rowbase + 16 * s + l15;
      const size_t obase = (((size_t)b * SB + rg) * NH + h) * HDIM + q4 * 4;
#pragma unroll
      for (int dt = 0; dt < 4; dt++) {
        u16x4 o;
        o[0] = f2bf(acc[s][dt][0] * linv);
        o[1] = f2bf(acc[s][dt][1] * linv);
        o[2] = f2bf(acc[s][dt][2] * linv);
        o[3] = f2bf(acc[s][dt][3] * linv);
        *(u16x4*)(Ow + obase + dt * 16) = o;
      }
    }
  }
}

extern "C" void kernel_launch(void* const* d_in, const int* in_sizes, int n_in,
                              void* d_out, int out_size, void* d_ws, size_t ws_size,
                              hipStream_t stream) {
  (void)in_sizes; (void)n_in; (void)out_size; (void)ws_size;
  const float* x  = (const float*)d_in[0];
  const int*   eff = (const int*)d_in[1];
  const float* Wq = (const float*)d_in[2];
  const float* bq = (const float*)d_in[3];
  const float* Wk = (const float*)d_in[4];
  const float* bk = (const float*)d_in[5];
  const float* Wv = (const float*)d_in[6];
  const float* bv = (const float*)d_in[7];
  const float* Wo = (const float*)d_in[8];
  const float* bo = (const float*)d_in[9];
  float* out = (float*)d_out;

  char* ws = (char*)d_ws;
  u16* Qw = (u16*)(ws);                        // 8 MB  bf16 (B,H,S,HD), pre-scaled
  u16* Kw = (u16*)(ws + (8u << 20));           // 8 MB  bf16 (B,H,S,HD)
  u16* Vt = (u16*)(ws + (16u << 20));          // 8 MB  bf16 (B,H,HD,S)  transposed
  u16* Ow = (u16*)(ws + (24u << 20));          // 8 MB  bf16 (B,S,H,HD)
  u16* xb = (u16*)(ws + (24u << 20));          // aliases Ow: xb dead before attn writes Ow
  u16* Wb3 = (u16*)(ws + (32u << 20));         // 6 MB  stacked bf16 [Wq;Wk;Wv]
  u16* Wob = (u16*)(ws + (38u << 20));         // 2 MB  bf16 Wo
  float* cosT = (float*)(ws + (40u << 20));    // 256 KB
  float* sinT = (float*)(ws + (40u << 20) + (256u << 10));

  // prep: x cvt (2048) + Wq/Wk/Wv cvt (3x512) + Wo cvt (512) + rope (256)
  hipLaunchKernelGGL(prep_kernel, dim3(4352), dim3(256), 0, stream,
                     x, Wq, Wk, Wv, Wo, xb, Wb3, Wob, cosT, sinT);

  hipLaunchKernelGGL(gemm_qkv_fused_kernel, dim3(32, 24), dim3(256), 0, stream,
                     xb, Wb3, bq, bk, bv, Qw, Kw, Vt, cosT, sinT);

  hipLaunchKernelGGL(attn_mfma_kernel, dim3(SB / 256, NH, NB), dim3(1024), 0, stream,
                     Qw, Kw, Vt, Ow, eff);

  hipLaunchKernelGGL(gemm_out_kernel, dim3(32, 16), dim3(256), 0, stream, Ow, Wob, bo, out);
}